// Round 1
// baseline (669.285 us; speedup 1.0000x reference)
//
#include <hip/hip_runtime.h>
#include <hip/hip_bf16.h>

#define BB 16384
#define EE 16
#define HH 256
#define CC 64
#define XD 320   // H + C
#define FH 1024  // 4H

typedef __attribute__((ext_vector_type(8))) short short8;
typedef __attribute__((ext_vector_type(4))) float f32x4;

__device__ inline unsigned short bfu(float x) {
    union { __hip_bfloat16 b; unsigned short u; } c;
    c.b = __float2bfloat16(x);
    return c.u;
}

// ---------------- anchor normalize ----------------
__global__ void anorm_kernel(const float* __restrict__ anchor, float* __restrict__ anorm) {
    int lane = threadIdx.x & 63;
    int wv = threadIdx.x >> 6;
    for (int e = wv; e < EE; e += 4) {
        float a = anchor[e * CC + lane];
        float s = a * a;
        #pragma unroll
        for (int off = 1; off < 64; off <<= 1) s += __shfl_xor(s, off, 64);
        anorm[e * CC + lane] = a / fmaxf(sqrtf(s), 1e-8f);
    }
}

// ---------------- router: one wave per token ----------------
__global__ __launch_bounds__(256) void router_kernel(
    const float* __restrict__ code_emb, const float* __restrict__ gumbel,
    const float* __restrict__ anorm,
    float* __restrict__ topw, int* __restrict__ tope,
    int* __restrict__ list, int* __restrict__ cnt)
{
    __shared__ float an[EE * CC];
    int tid = threadIdx.x;
    for (int i = tid; i < EE * CC; i += 256) an[i] = anorm[i];
    __syncthreads();

    int lane = tid & 63;
    int wv = tid >> 6;
    int b = blockIdx.x * 4 + wv;

    float c = code_emb[b * CC + lane];
    float nrm = c * c;
    #pragma unroll
    for (int off = 1; off < 64; off <<= 1) nrm += __shfl_xor(nrm, off, 64);
    float inv = 0.125f / fmaxf(sqrtf(nrm), 1e-8f);

    float t = 0.f;
    #pragma unroll
    for (int e = 0; e < EE; ++e) {
        float p = c * an[e * CC + lane];
        #pragma unroll
        for (int off = 1; off < 64; off <<= 1) p += __shfl_xor(p, off, 64);
        if (lane == e) t = p;
    }
    float g = (lane < EE) ? gumbel[b * EE + lane] : 0.f;
    float z = (t * inv + g) * 2.0f;   // (logit+gumbel)/TAU, TAU=0.5

    // softmax across 16 lanes (xor network stays within 16-lane groups)
    float m = z;
    #pragma unroll
    for (int off = 1; off < 16; off <<= 1) m = fmaxf(m, __shfl_xor(m, off, 64));
    float p = expf(z - m);
    float s = p;
    #pragma unroll
    for (int off = 1; off < 16; off <<= 1) s += __shfl_xor(s, off, 64);
    float w = p / s;

    // top-2, lowest-index tie-break, redundantly on all lanes
    float best = -1.f, second = -1.f;
    int bi = 0, si = 0;
    #pragma unroll
    for (int j = 0; j < EE; ++j) {
        float wj = __shfl(w, j, 64);
        if (wj > best) { second = best; si = bi; best = wj; bi = j; }
        else if (wj > second) { second = wj; si = j; }
    }
    if (lane == 0) {
        int p0 = b * 2, p1 = b * 2 + 1;
        topw[p0] = best;   tope[p0] = bi;
        topw[p1] = second; tope[p1] = si;
        int q0 = atomicAdd(&cnt[bi], 1);
        list[bi * BB + q0] = p0;
        int q1 = atomicAdd(&cnt[si], 1);
        list[si * BB + q1] = p1;
    }
}

// ---------------- weight conversion f32 -> bf16 ----------------
__global__ void convert_w_kernel(const float* __restrict__ W1, const float* __restrict__ W2,
                                 __hip_bfloat16* __restrict__ W1bf, __hip_bfloat16* __restrict__ W2bf) {
    int i = blockIdx.x * blockDim.x + threadIdx.x;
    const int n1 = EE * FH * XD / 4;
    const int n2 = EE * HH * FH / 4;
    if (i < n1) {
        float4 v = ((const float4*)W1)[i];
        ushort4 o; o.x = bfu(v.x); o.y = bfu(v.y); o.z = bfu(v.z); o.w = bfu(v.w);
        ((ushort4*)W1bf)[i] = o;
    } else if (i < n1 + n2) {
        int j = i - n1;
        float4 v = ((const float4*)W2)[j];
        ushort4 o; o.x = bfu(v.x); o.y = bfu(v.y); o.z = bfu(v.z); o.w = bfu(v.w);
        ((ushort4*)W2bf)[j] = o;
    }
}

// ---------------- x = concat(h, code_emb) -> bf16 ----------------
__global__ void convert_x_kernel(const float* __restrict__ h, const float* __restrict__ ce,
                                 __hip_bfloat16* __restrict__ xbf) {
    int i = blockIdx.x * blockDim.x + threadIdx.x;  // group of 4 elements
    const int n = BB * XD / 4;
    if (i >= n) return;
    int i4 = i * 4;
    int b = i4 / XD;
    int c = i4 % XD;
    float4 v;
    if (c < HH) v = *(const float4*)&h[b * HH + c];
    else        v = *(const float4*)&ce[b * CC + (c - HH)];
    ushort4 o; o.x = bfu(v.x); o.y = bfu(v.y); o.z = bfu(v.z); o.w = bfu(v.w);
    ((ushort4*)xbf)[i] = o;
}

// ---------------- aux loss (deterministic reduction) ----------------
__global__ __launch_bounds__(256) void aux_kernel(const float* __restrict__ topw,
                                                  const int* __restrict__ tope,
                                                  float* __restrict__ out) {
    __shared__ float ls[256][EE + 1];
    __shared__ float counts[EE];
    int tid = threadIdx.x;
    #pragma unroll
    for (int e = 0; e < EE; ++e) ls[tid][e] = 0.f;
    for (int i = tid; i < 2 * BB; i += 256) ls[tid][tope[i]] += topw[i];
    __syncthreads();
    if (tid < EE) {
        float s = 0.f;
        for (int r = 0; r < 256; ++r) s += ls[r][tid];
        counts[tid] = s;
    }
    __syncthreads();
    if (tid == 0) {
        float total = 0.f;
        for (int e = 0; e < EE; ++e) total += counts[e];
        float mean = total / EE;
        float var = 0.f;
        for (int e = 0; e < EE; ++e) { float d = counts[e] - mean; var += d * d; }
        var /= (EE - 1);
        float ent = 0.f;
        for (int e = 0; e < EE; ++e) { float ld = counts[e] / total; ent -= ld * logf(ld + 1e-12f); }
        out[(size_t)BB * HH] = 0.5f * (sqrtf(var) + ent);
    }
}

// ---------------- fused sparse MoE MLP ----------------
// grid (E, 32), 256 threads. 64-token tile per iteration, 4 waves split N.
__global__ __launch_bounds__(256, 2) void moe_kernel(
    const __hip_bfloat16* __restrict__ xbf,
    const __hip_bfloat16* __restrict__ W1bf,
    const __hip_bfloat16* __restrict__ W2bf,
    const float* __restrict__ b1, const float* __restrict__ b2,
    const int* __restrict__ list, const int* __restrict__ cnt,
    const float* __restrict__ topw,
    float* __restrict__ tmp)
{
    __shared__ __hip_bfloat16 xs[64][328];  // +8 pad -> 4-bank row shift
    __shared__ __hip_bfloat16 hs[64][72];   // +8 pad
    const int e = blockIdx.x;
    const int n = cnt[e];
    const int tid = threadIdx.x;
    const int lane = tid & 63;
    const int wv = tid >> 6;     // 0..3
    const int l15 = lane & 15;
    const int kg = lane >> 4;    // 0..3

    const __hip_bfloat16* w1e = W1bf + (size_t)e * FH * XD;
    const __hip_bfloat16* w2e = W2bf + (size_t)e * HH * FH;

    for (int tile = blockIdx.y; tile * 64 < n; tile += gridDim.y) {
        const int base = tile * 64;
        const int nv = min(64, n - base);

        // gather x rows: 4 threads per row, 80 bf16 each (10x16B)
        {
            int row = tid >> 2, part = tid & 3;
            ulonglong2* dst = (ulonglong2*)&xs[row][part * 80];
            if (row < nv) {
                int pair = list[e * BB + base + row];
                const ulonglong2* src = (const ulonglong2*)(xbf + (size_t)(pair >> 1) * XD + part * 80);
                #pragma unroll
                for (int i = 0; i < 10; ++i) dst[i] = src[i];
            } else {
                ulonglong2 zz; zz.x = 0ull; zz.y = 0ull;
                #pragma unroll
                for (int i = 0; i < 10; ++i) dst[i] = zz;
            }
        }
        __syncthreads();

        f32x4 acc[4][4];
        #pragma unroll
        for (int mi = 0; mi < 4; ++mi)
            #pragma unroll
            for (int nf = 0; nf < 4; ++nf)
                acc[mi][nf] = (f32x4){0.f, 0.f, 0.f, 0.f};

        for (int oc = 0; oc < 16; ++oc) {
            // GEMM1: pre[64 tok][16 o-cols per wave], K=320
            f32x4 pre[4];
            #pragma unroll
            for (int mi = 0; mi < 4; ++mi) pre[mi] = (f32x4){0.f, 0.f, 0.f, 0.f};
            const __hip_bfloat16* w1c = w1e + (size_t)(oc * 64 + wv * 16 + l15) * XD + kg * 8;
            #pragma unroll
            for (int ks = 0; ks < 10; ++ks) {
                short8 bfrag = *(const short8*)(w1c + ks * 32);
                #pragma unroll
                for (int mi = 0; mi < 4; ++mi) {
                    short8 a = *(const short8*)&xs[mi * 16 + l15][ks * 32 + kg * 8];
                    pre[mi] = __builtin_amdgcn_mfma_f32_16x16x32_bf16(a, bfrag, pre[mi], 0, 0, 0);
                }
            }
            // bias + exact gelu -> hs (bf16)
            float b1v = b1[e * FH + oc * 64 + wv * 16 + l15];
            __syncthreads();
            #pragma unroll
            for (int mi = 0; mi < 4; ++mi) {
                #pragma unroll
                for (int r = 0; r < 4; ++r) {
                    float v = pre[mi][r] + b1v;
                    float gl = 0.5f * v * (1.0f + erff(v * 0.70710678118654752f));
                    hs[mi * 16 + kg * 4 + r][wv * 16 + l15] = __float2bfloat16(gl);
                }
            }
            __syncthreads();
            // GEMM2: acc[64 tok][64 d-cols per wave] += hid @ W2^T (K=64 chunk)
            const __hip_bfloat16* w2c = w2e + (size_t)(wv * 64 + l15) * FH + oc * 64 + kg * 8;
            #pragma unroll
            for (int ks = 0; ks < 2; ++ks) {
                short8 a[4];
                #pragma unroll
                for (int mi = 0; mi < 4; ++mi)
                    a[mi] = *(const short8*)&hs[mi * 16 + l15][ks * 32 + kg * 8];
                #pragma unroll
                for (int nf = 0; nf < 4; ++nf) {
                    short8 bfrag = *(const short8*)(w2c + (size_t)(nf * 16) * FH + ks * 32);
                    #pragma unroll
                    for (int mi = 0; mi < 4; ++mi)
                        acc[mi][nf] = __builtin_amdgcn_mfma_f32_16x16x32_bf16(a[mi], bfrag, acc[mi][nf], 0, 0, 0);
                }
            }
        }

        // epilogue: +b2, *routing weight, scatter to per-pair scratch
        #pragma unroll
        for (int mi = 0; mi < 4; ++mi) {
            #pragma unroll
            for (int r = 0; r < 4; ++r) {
                int row = mi * 16 + kg * 4 + r;
                if (row < nv) {
                    int pair = list[e * BB + base + row];
                    float w = topw[pair];
                    float* dst = tmp + (size_t)pair * HH + wv * 64;
                    #pragma unroll
                    for (int nf = 0; nf < 4; ++nf) {
                        int d = wv * 64 + nf * 16 + l15;
                        dst[nf * 16 + l15] = w * (acc[mi][nf][r] + b2[e * HH + d]);
                    }
                }
            }
        }
        __syncthreads();  // protect xs before next tile's gather
    }
}

// ---------------- combine the two expert slots ----------------
__global__ void combine_kernel(const float* __restrict__ tmp, float* __restrict__ out) {
    int i = blockIdx.x * blockDim.x + threadIdx.x;  // float4 index over [B*256/4)
    int b = i >> 6;
    int d4 = i & 63;
    const float4* t0 = (const float4*)(tmp + (size_t)b * 512);
    float4 a = t0[d4];
    float4 c = t0[64 + d4];
    float4 o;
    o.x = a.x + c.x; o.y = a.y + c.y; o.z = a.z + c.z; o.w = a.w + c.w;
    ((float4*)out)[i] = o;
}

extern "C" void kernel_launch(void* const* d_in, const int* in_sizes, int n_in,
                              void* d_out, int out_size, void* d_ws, size_t ws_size,
                              hipStream_t stream) {
    const float* h   = (const float*)d_in[0];
    const float* ce  = (const float*)d_in[1];
    const float* anc = (const float*)d_in[2];
    const float* W1  = (const float*)d_in[3];
    const float* b1  = (const float*)d_in[4];
    const float* W2  = (const float*)d_in[5];
    const float* b2  = (const float*)d_in[6];
    const float* gum = (const float*)d_in[7];
    float* out = (float*)d_out;

    char* ws = (char*)d_ws;
    size_t off = 0;
    auto alloc = [&](size_t bytes) {
        char* p = ws + off;
        off = (off + bytes + 255) & ~(size_t)255;
        return p;
    };
    __hip_bfloat16* W1bf = (__hip_bfloat16*)alloc((size_t)EE * FH * XD * 2);
    __hip_bfloat16* W2bf = (__hip_bfloat16*)alloc((size_t)EE * HH * FH * 2);
    __hip_bfloat16* xbf  = (__hip_bfloat16*)alloc((size_t)BB * XD * 2);
    float* tmp  = (float*)alloc((size_t)BB * 2 * HH * 4);
    float* topw = (float*)alloc((size_t)BB * 2 * 4);
    int*   tope = (int*)alloc((size_t)BB * 2 * 4);
    int*   list = (int*)alloc((size_t)EE * BB * 4);
    int*   cnt  = (int*)alloc(EE * 4);
    float* anorm = (float*)alloc(EE * CC * 4);

    hipMemsetAsync(cnt, 0, EE * 4, stream);
    anorm_kernel<<<1, 256, 0, stream>>>(anc, anorm);
    router_kernel<<<BB / 4, 256, 0, stream>>>(ce, gum, anorm, topw, tope, list, cnt);
    convert_w_kernel<<<((EE * FH * XD + EE * HH * FH) / 4 + 255) / 256, 256, 0, stream>>>(W1, W2, W1bf, W2bf);
    convert_x_kernel<<<(BB * XD / 4 + 255) / 256, 256, 0, stream>>>(h, ce, xbf);
    aux_kernel<<<1, 256, 0, stream>>>(topw, tope, out);
    moe_kernel<<<dim3(EE, 32), 256, 0, stream>>>(xbf, W1bf, W2bf, b1, b2, list, cnt, topw, tmp);
    combine_kernel<<<(BB * HH / 4) / 256, 256, 0, stream>>>(tmp, out);
}

// Round 2
// 299.836 us; speedup vs baseline: 2.2322x; 2.2322x over previous
//
#include <hip/hip_runtime.h>
#include <hip/hip_bf16.h>

#define BB 16384
#define EE 16
#define HH 256
#define CC 64
#define XD 320   // H + C
#define FH 1024  // 4H
#define CNTP 16  // cnt padding stride (one counter per 64B line)

typedef __attribute__((ext_vector_type(8))) short short8;
typedef __attribute__((ext_vector_type(4))) float f32x4;

__device__ inline unsigned short bfu(float x) {
    union { __hip_bfloat16 b; unsigned short u; } c;
    c.b = __float2bfloat16(x);
    return c.u;
}

// ---------------- anchor normalize ----------------
__global__ void anorm_kernel(const float* __restrict__ anchor, float* __restrict__ anorm) {
    int lane = threadIdx.x & 63;
    int wv = threadIdx.x >> 6;
    for (int e = wv; e < EE; e += 4) {
        float a = anchor[e * CC + lane];
        float s = a * a;
        #pragma unroll
        for (int off = 1; off < 64; off <<= 1) s += __shfl_xor(s, off, 64);
        anorm[e * CC + lane] = a / fmaxf(sqrtf(s), 1e-8f);
    }
}

// ---------------- router: 16 tokens x 16 experts per block, no atomics ----------------
__global__ __launch_bounds__(256) void router_kernel(
    const float* __restrict__ code_emb, const float* __restrict__ gumbel,
    const float* __restrict__ anorm,
    float* __restrict__ topw, int* __restrict__ tope)
{
    __shared__ float an_s[EE][68];
    __shared__ float ce_s[16][68];
    __shared__ float inrm[16];
    const int tid = threadIdx.x;

    // stage normalized anchors (1024 f32) and 16 ce rows (1024 f32)
    {
        int idx = tid * 4;
        int r = idx >> 6, k = idx & 63;
        *(float4*)&an_s[r][k] = *(const float4*)&anorm[idx];
        *(float4*)&ce_s[r][k] = *(const float4*)&code_emb[blockIdx.x * 1024 + idx];
    }
    __syncthreads();

    const int tok = tid >> 4;
    const int e = tid & 15;
    if (e == 0) {
        float s = 0.f;
        #pragma unroll
        for (int k = 0; k < 64; ++k) { float c = ce_s[tok][k]; s += c * c; }
        inrm[tok] = 0.125f / fmaxf(sqrtf(s), 1e-8f);
    }
    __syncthreads();

    float dot = 0.f;
    #pragma unroll
    for (int k = 0; k < 64; ++k) dot += ce_s[tok][k] * an_s[e][k];

    const int b = blockIdx.x * 16 + tok;
    float z = (dot * inrm[tok] + gumbel[b * EE + e]) * 2.0f;  // /TAU, TAU=0.5

    // softmax over the 16-lane group
    float m = z;
    #pragma unroll
    for (int off = 1; off < 16; off <<= 1) m = fmaxf(m, __shfl_xor(m, off, 64));
    float p = expf(z - m);
    float s = p;
    #pragma unroll
    for (int off = 1; off < 16; off <<= 1) s += __shfl_xor(s, off, 64);
    float w = p / s;

    // top-2 (lowest-index tie-break), redundant across the 16-lane group
    const int lbase = (tid & 63) & 48;
    float best = -1.f, second = -1.f;
    int bi = 0, si = 0;
    #pragma unroll
    for (int j = 0; j < EE; ++j) {
        float wj = __shfl(w, lbase + j, 64);
        if (wj > best) { second = best; si = bi; best = wj; bi = j; }
        else if (wj > second) { second = wj; si = j; }
    }
    if (e == 0) {
        topw[b * 2] = best;       tope[b * 2] = bi;
        topw[b * 2 + 1] = second; tope[b * 2 + 1] = si;
    }
}

// ---------------- counting-sort assignment: 512 pairs per block ----------------
__global__ __launch_bounds__(256) void assign_kernel(
    const int* __restrict__ tope, int* __restrict__ list, int* __restrict__ cnt)
{
    __shared__ int lcnt[EE];
    __shared__ int base[EE];
    const int tid = threadIdx.x;
    if (tid < EE) lcnt[tid] = 0;
    __syncthreads();
    const int p0 = blockIdx.x * 512;
    const int e0 = tope[p0 + tid];
    const int e1 = tope[p0 + 256 + tid];
    const int r0 = atomicAdd(&lcnt[e0], 1);
    const int r1 = atomicAdd(&lcnt[e1], 1);
    __syncthreads();
    if (tid < EE) base[tid] = atomicAdd(&cnt[tid * CNTP], lcnt[tid]);
    __syncthreads();
    list[e0 * BB + base[e0] + r0] = p0 + tid;
    list[e1 * BB + base[e1] + r1] = p0 + 256 + tid;
}

// ---------------- weight conversion f32 -> bf16 ----------------
__global__ void convert_w_kernel(const float* __restrict__ W1, const float* __restrict__ W2,
                                 __hip_bfloat16* __restrict__ W1bf, __hip_bfloat16* __restrict__ W2bf) {
    int i = blockIdx.x * blockDim.x + threadIdx.x;
    const int n1 = EE * FH * XD / 4;
    const int n2 = EE * HH * FH / 4;
    if (i < n1) {
        float4 v = ((const float4*)W1)[i];
        ushort4 o; o.x = bfu(v.x); o.y = bfu(v.y); o.z = bfu(v.z); o.w = bfu(v.w);
        ((ushort4*)W1bf)[i] = o;
    } else if (i < n1 + n2) {
        int j = i - n1;
        float4 v = ((const float4*)W2)[j];
        ushort4 o; o.x = bfu(v.x); o.y = bfu(v.y); o.z = bfu(v.z); o.w = bfu(v.w);
        ((ushort4*)W2bf)[j] = o;
    }
}

// ---------------- x = concat(h, code_emb) -> bf16 ----------------
__global__ void convert_x_kernel(const float* __restrict__ h, const float* __restrict__ ce,
                                 __hip_bfloat16* __restrict__ xbf) {
    int i = blockIdx.x * blockDim.x + threadIdx.x;  // group of 4 elements
    const int n = BB * XD / 4;
    if (i >= n) return;
    int i4 = i * 4;
    int b = i4 / XD;
    int c = i4 % XD;
    float4 v;
    if (c < HH) v = *(const float4*)&h[b * HH + c];
    else        v = *(const float4*)&ce[b * CC + (c - HH)];
    ushort4 o; o.x = bfu(v.x); o.y = bfu(v.y); o.z = bfu(v.z); o.w = bfu(v.w);
    ((ushort4*)xbf)[i] = o;
}

// ---------------- aux loss (deterministic reduction) ----------------
__global__ __launch_bounds__(256) void aux_kernel(const float* __restrict__ topw,
                                                  const int* __restrict__ tope,
                                                  float* __restrict__ out) {
    __shared__ float ls[256][EE + 1];
    __shared__ float counts[EE];
    int tid = threadIdx.x;
    #pragma unroll
    for (int e = 0; e < EE; ++e) ls[tid][e] = 0.f;
    for (int i = tid; i < 2 * BB; i += 256) ls[tid][tope[i]] += topw[i];
    __syncthreads();
    if (tid < EE) {
        float s = 0.f;
        for (int r = 0; r < 256; ++r) s += ls[r][tid];
        counts[tid] = s;
    }
    __syncthreads();
    if (tid == 0) {
        float total = 0.f;
        for (int e = 0; e < EE; ++e) total += counts[e];
        float mean = total / EE;
        float var = 0.f;
        for (int e = 0; e < EE; ++e) { float d = counts[e] - mean; var += d * d; }
        var /= (EE - 1);
        float ent = 0.f;
        for (int e = 0; e < EE; ++e) { float ld = counts[e] / total; ent -= ld * logf(ld + 1e-12f); }
        out[(size_t)BB * HH] = 0.5f * (sqrtf(var) + ent);
    }
}

// ---------------- fused sparse MoE MLP ----------------
// grid (E, 32), 256 threads. 64-token tile per iteration, 4 waves split N.
__global__ __launch_bounds__(256, 2) void moe_kernel(
    const __hip_bfloat16* __restrict__ xbf,
    const __hip_bfloat16* __restrict__ W1bf,
    const __hip_bfloat16* __restrict__ W2bf,
    const float* __restrict__ b1, const float* __restrict__ b2,
    const int* __restrict__ list, const int* __restrict__ cnt,
    const float* __restrict__ topw,
    float* __restrict__ tmp)
{
    __shared__ __hip_bfloat16 xs[64][328];  // +8 pad -> 4-bank row shift
    __shared__ __hip_bfloat16 hs[64][72];   // +8 pad
    const int e = blockIdx.x;
    const int n = cnt[e * CNTP];
    const int tid = threadIdx.x;
    const int lane = tid & 63;
    const int wv = tid >> 6;     // 0..3
    const int l15 = lane & 15;
    const int kg = lane >> 4;    // 0..3

    const __hip_bfloat16* w1e = W1bf + (size_t)e * FH * XD;
    const __hip_bfloat16* w2e = W2bf + (size_t)e * HH * FH;

    for (int tile = blockIdx.y; tile * 64 < n; tile += gridDim.y) {
        const int base = tile * 64;
        const int nv = min(64, n - base);

        // gather x rows: 4 threads per row, 80 bf16 each (10x16B)
        {
            int row = tid >> 2, part = tid & 3;
            ulonglong2* dst = (ulonglong2*)&xs[row][part * 80];
            if (row < nv) {
                int pair = list[e * BB + base + row];
                const ulonglong2* src = (const ulonglong2*)(xbf + (size_t)(pair >> 1) * XD + part * 80);
                #pragma unroll
                for (int i = 0; i < 10; ++i) dst[i] = src[i];
            } else {
                ulonglong2 zz; zz.x = 0ull; zz.y = 0ull;
                #pragma unroll
                for (int i = 0; i < 10; ++i) dst[i] = zz;
            }
        }
        __syncthreads();

        f32x4 acc[4][4];
        #pragma unroll
        for (int mi = 0; mi < 4; ++mi)
            #pragma unroll
            for (int nf = 0; nf < 4; ++nf)
                acc[mi][nf] = (f32x4){0.f, 0.f, 0.f, 0.f};

        for (int oc = 0; oc < 16; ++oc) {
            // GEMM1: pre[64 tok][16 o-cols per wave], K=320
            f32x4 pre[4];
            #pragma unroll
            for (int mi = 0; mi < 4; ++mi) pre[mi] = (f32x4){0.f, 0.f, 0.f, 0.f};
            const __hip_bfloat16* w1c = w1e + (size_t)(oc * 64 + wv * 16 + l15) * XD + kg * 8;
            #pragma unroll
            for (int ks = 0; ks < 10; ++ks) {
                short8 bfrag = *(const short8*)(w1c + ks * 32);
                #pragma unroll
                for (int mi = 0; mi < 4; ++mi) {
                    short8 a = *(const short8*)&xs[mi * 16 + l15][ks * 32 + kg * 8];
                    pre[mi] = __builtin_amdgcn_mfma_f32_16x16x32_bf16(a, bfrag, pre[mi], 0, 0, 0);
                }
            }
            // bias + exact gelu -> hs (bf16)
            float b1v = b1[e * FH + oc * 64 + wv * 16 + l15];
            __syncthreads();
            #pragma unroll
            for (int mi = 0; mi < 4; ++mi) {
                #pragma unroll
                for (int r = 0; r < 4; ++r) {
                    float v = pre[mi][r] + b1v;
                    float gl = 0.5f * v * (1.0f + erff(v * 0.70710678118654752f));
                    hs[mi * 16 + kg * 4 + r][wv * 16 + l15] = __float2bfloat16(gl);
                }
            }
            __syncthreads();
            // GEMM2: acc[64 tok][64 d-cols per wave] += hid @ W2^T (K=64 chunk)
            const __hip_bfloat16* w2c = w2e + (size_t)(wv * 64 + l15) * FH + oc * 64 + kg * 8;
            #pragma unroll
            for (int ks = 0; ks < 2; ++ks) {
                short8 a[4];
                #pragma unroll
                for (int mi = 0; mi < 4; ++mi)
                    a[mi] = *(const short8*)&hs[mi * 16 + l15][ks * 32 + kg * 8];
                #pragma unroll
                for (int nf = 0; nf < 4; ++nf) {
                    short8 bfrag = *(const short8*)(w2c + (size_t)(nf * 16) * FH + ks * 32);
                    #pragma unroll
                    for (int mi = 0; mi < 4; ++mi)
                        acc[mi][nf] = __builtin_amdgcn_mfma_f32_16x16x32_bf16(a[mi], bfrag, acc[mi][nf], 0, 0, 0);
                }
            }
        }

        // epilogue: +b2, *routing weight, scatter to per-pair scratch
        #pragma unroll
        for (int mi = 0; mi < 4; ++mi) {
            #pragma unroll
            for (int r = 0; r < 4; ++r) {
                int row = mi * 16 + kg * 4 + r;
                if (row < nv) {
                    int pair = list[e * BB + base + row];
                    float w = topw[pair];
                    float* dst = tmp + (size_t)pair * HH + wv * 64;
                    #pragma unroll
                    for (int nf = 0; nf < 4; ++nf) {
                        int d = wv * 64 + nf * 16 + l15;
                        dst[nf * 16 + l15] = w * (acc[mi][nf][r] + b2[e * HH + d]);
                    }
                }
            }
        }
        __syncthreads();  // protect xs before next tile's gather
    }
}

// ---------------- combine the two expert slots ----------------
__global__ void combine_kernel(const float* __restrict__ tmp, float* __restrict__ out) {
    int i = blockIdx.x * blockDim.x + threadIdx.x;  // float4 index over [B*256/4)
    int b = i >> 6;
    int d4 = i & 63;
    const float4* t0 = (const float4*)(tmp + (size_t)b * 512);
    float4 a = t0[d4];
    float4 c = t0[64 + d4];
    float4 o;
    o.x = a.x + c.x; o.y = a.y + c.y; o.z = a.z + c.z; o.w = a.w + c.w;
    ((float4*)out)[i] = o;
}

extern "C" void kernel_launch(void* const* d_in, const int* in_sizes, int n_in,
                              void* d_out, int out_size, void* d_ws, size_t ws_size,
                              hipStream_t stream) {
    const float* h   = (const float*)d_in[0];
    const float* ce  = (const float*)d_in[1];
    const float* anc = (const float*)d_in[2];
    const float* W1  = (const float*)d_in[3];
    const float* b1  = (const float*)d_in[4];
    const float* W2  = (const float*)d_in[5];
    const float* b2  = (const float*)d_in[6];
    const float* gum = (const float*)d_in[7];
    float* out = (float*)d_out;

    char* ws = (char*)d_ws;
    size_t off = 0;
    auto alloc = [&](size_t bytes) {
        char* p = ws + off;
        off = (off + bytes + 255) & ~(size_t)255;
        return p;
    };
    __hip_bfloat16* W1bf = (__hip_bfloat16*)alloc((size_t)EE * FH * XD * 2);
    __hip_bfloat16* W2bf = (__hip_bfloat16*)alloc((size_t)EE * HH * FH * 2);
    __hip_bfloat16* xbf  = (__hip_bfloat16*)alloc((size_t)BB * XD * 2);
    float* tmp  = (float*)alloc((size_t)BB * 2 * HH * 4);
    float* topw = (float*)alloc((size_t)BB * 2 * 4);
    int*   tope = (int*)alloc((size_t)BB * 2 * 4);
    int*   list = (int*)alloc((size_t)EE * BB * 4);
    int*   cnt  = (int*)alloc(EE * CNTP * 4);
    float* anorm = (float*)alloc(EE * CC * 4);

    hipMemsetAsync(cnt, 0, EE * CNTP * 4, stream);
    anorm_kernel<<<1, 256, 0, stream>>>(anc, anorm);
    router_kernel<<<BB / 16, 256, 0, stream>>>(ce, gum, anorm, topw, tope);
    assign_kernel<<<2 * BB / 512, 256, 0, stream>>>(tope, list, cnt);
    convert_w_kernel<<<((EE * FH * XD + EE * HH * FH) / 4 + 255) / 256, 256, 0, stream>>>(W1, W2, W1bf, W2bf);
    convert_x_kernel<<<(BB * XD / 4 + 255) / 256, 256, 0, stream>>>(h, ce, xbf);
    aux_kernel<<<1, 256, 0, stream>>>(topw, tope, out);
    moe_kernel<<<dim3(EE, 32), 256, 0, stream>>>(xbf, W1bf, W2bf, b1, b2, list, cnt, topw, tmp);
    combine_kernel<<<(BB * HH / 4) / 256, 256, 0, stream>>>(tmp, out);
}